// Round 11
// baseline (195.894 us; speedup 1.0000x reference)
//
#include <hip/hip_runtime.h>
#include <cstdint>

// Dynamic_MLP_C: fused bf16-MFMA implementation.
//
// Reformulation: x[t,o] = sum_k A[t,k] * B[k,o],  k = j*64+i  (K = 4160)
//   A[t, j*64+i] = w21[t,j] * w12[t,i]  (rank-1), bias rows A[t,4096+i]=w12[t,i].
// Re-association: x[t,o] = sum_j w21[t,j] * (w12[t,:] @ B_j)[o]
//   -> A-fragment = CONSTANT w12 regs; per j: 2 MFMAs -> m; acc += w21[t,j]*m.
//
// R7-R10: barrier-free K-loop, B straight from L2 to named VGPR buffers
// (532 KB fits per-XCD L2; prep layout -> 1 KB contiguous wave-loads).
// R11: compiler self-capped at 128 VGPRs (targets 4 waves/EU despite
// launch_bounds min=2) -> forced tiny tiles. Pin occupancy with
// amdgpu_waves_per_eu(2,2) -> 256-VGPR budget, and double tokens/wave
// (mf=8: 128 tok x 16 cols). A wave's B traffic is token-count-independent,
// so total L2 B-delivery HALVES (272->136 MB); MFMA/VALU per chunk become
// balanced (~310 vs ~280 cyc/SIMD). Live set ~190 <= 256 -> no spill.

typedef __bf16 bf16x4 __attribute__((ext_vector_type(4)));
typedef __bf16 bf16x8 __attribute__((ext_vector_type(8)));
typedef float  f32x4  __attribute__((ext_vector_type(4)));

#define MFMA16(A, B, C) __builtin_amdgcn_mfma_f32_16x16x32_bf16(A, B, C, 0, 0, 0)

// workspace element offsets (bf16 elements)
#define OFF_BT22 0         // K=4160 grouped layout, 266240 elems
#define OFF_W11  266240    // K=128,  8192 (frag layout)
#define OFF_W21  274432    // K=128,  8192
#define OFF_W12  282624    // K=64,   4096
#define OFF_W3   286720    // K=64,   4096

// prep: [64 k x 64 o] fp32 tile -> bf16.
//  W22/b22 tiles: grouped layout ws[((o>>4)*520 + k8)*128 + (o&15)*8 + (k&7)]
//  small weights: frag layout    ws[base + (k>>3)*512 + o*8 + (k&7)]
__global__ __launch_bounds__(256) void prep_kernel(
    const float* __restrict__ W22, const float* __restrict__ b22,
    const float* __restrict__ W11, const float* __restrict__ W21,
    const float* __restrict__ W12, const float* __restrict__ W3,
    __bf16* __restrict__ ws)
{
    __shared__ __bf16 T[64][72];
    const int b = blockIdx.x, tid = threadIdx.x;
    const float* src; long base = 0;
    if (b < 64)       { src = W22 + b * 4096; }
    else if (b == 64) { src = b22; }
    else if (b < 67)  { src = W11 + (b - 65) * 4096; base = OFF_W11 + (b - 65) * 4096; }
    else if (b < 69)  { src = W21 + (b - 67) * 4096; base = OFF_W21 + (b - 67) * 4096; }
    else if (b == 69) { src = W12;                   base = OFF_W12; }
    else              { src = W3;                    base = OFF_W3; }
    #pragma unroll
    for (int it = 0; it < 4; ++it) {
        int u = it * 1024 + tid * 4;
        int r = u >> 6, c = u & 63;
        const float4 v = *(const float4*)(src + u);
        T[r][c] = (__bf16)v.x; T[r][c + 1] = (__bf16)v.y;
        T[r][c + 2] = (__bf16)v.z; T[r][c + 3] = (__bf16)v.w;
    }
    __syncthreads();
    #pragma unroll
    for (int it = 0; it < 2; ++it) {
        int item = it * 256 + tid;
        int q = item >> 6, o = item & 63;
        bf16x8 pk;
        #pragma unroll
        for (int kj = 0; kj < 8; ++kj) pk[kj] = T[q * 8 + kj][o];
        long dstE;
        if (b <= 64) {
            int k8 = (b == 64 ? 512 : b * 8) + q;
            dstE = OFF_BT22 + ((long)(o >> 4) * 520 + k8) * 128 + (o & 15) * 8;
        } else {
            dstE = base + q * 512 + o * 8;
        }
        *(bf16x8*)(ws + dstE) = pk;
    }
}

// ---- register chunk-buffer machinery: named registers, token-pasted ----
#define LOADCH(buf, c) do {                                          \
    buf##_0 = *(const bf16x8*)(Bw + ((c)*16 +  0) * 128);            \
    buf##_1 = *(const bf16x8*)(Bw + ((c)*16 +  4) * 128);            \
    buf##_2 = *(const bf16x8*)(Bw + ((c)*16 +  8) * 128);            \
    buf##_3 = *(const bf16x8*)(Bw + ((c)*16 + 12) * 128);            \
} while (0)

#define COMPUTE_J(b0, b1, j) do {                                    \
    f32x4 w4[8];                                                     \
    _Pragma("unroll")                                                \
    for (int mf = 0; mf < 8; ++mf) {                                 \
        bf16x4 wv4 = *(const bf16x4*)(w21T + (j)*132 + mf*16 + quad*4);\
        w4[mf] = __builtin_convertvector(wv4, f32x4);                \
    }                                                                \
    _Pragma("unroll")                                                \
    for (int mf = 0; mf < 8; ++mf) {                                 \
        f32x4 fz = {};                                               \
        f32x4 m = MFMA16(a12[mf][0], b0, fz);                        \
        m       = MFMA16(a12[mf][1], b1, m);                         \
        _Pragma("unroll")                                            \
        for (int r = 0; r < 4; ++r)                                  \
            acc[mf][r] = fmaf(w4[mf][r], m[r], acc[mf][r]);          \
    }                                                                \
} while (0)

#define COMPUTE(buf, c) do {                                         \
    COMPUTE_J(buf##_0, buf##_1, (c)*2);                              \
    COMPUTE_J(buf##_2, buf##_3, (c)*2 + 1);                          \
} while (0)

__global__ __launch_bounds__(256)
__attribute__((amdgpu_waves_per_eu(2, 2)))
void main_kernel(
    const float* __restrict__ img, const float* __restrict__ loc,
    const float* __restrict__ b11, const float* __restrict__ b12,
    const float* __restrict__ b21, const float* __restrict__ ln_g,
    const float* __restrict__ ln_b, const float* __restrict__ b3,
    const __bf16* __restrict__ ws, float* __restrict__ out)
{
    // LDS carve (70144 B, 2 blocks/CU at 160 KB):
    //  [0,34816)      catL [128][136] bf16 (dead after P1); overlays:
    //    [0,18432)     w12L [128][72] bf16 (written P2, read for a12 frags)
    //    [18432,22528) ps   [128][4] float2 (LN partials, written P4)
    //  [34816,53248)  w11L [128][72] bf16 (last read P2) -> xL in P4/P5
    //  [53248,70144)  w21T [64 j][132 t] bf16 (transposed, read in K-loop)
    __shared__ __align__(1024) char smem[70144];
    __bf16* catL = (__bf16*)smem;
    __bf16* w12L = (__bf16*)smem;
    float2* ps   = (float2*)(smem + 18432);
    __bf16* w11L = (__bf16*)(smem + 34816);
    __bf16* xL   = w11L;
    __bf16* w21T = (__bf16*)(smem + 53248);

    const int tid  = threadIdx.x;
    const int wv   = tid >> 6;
    const int lane = tid & 63;
    const int ln   = lane & 15;     // A-row / C-col / B-col lane index
    const int quad = lane >> 4;     // k-quad / C-row group
    const int ob   = wv * 16;       // this wave's 16 o-cols (= col-group wv)
    const long tb  = (long)blockIdx.x * 128;

    const __bf16* Bt22  = ws + OFF_BT22;
    const __bf16* W11bt = ws + OFF_W11;
    const __bf16* W21bt = ws + OFF_W21;
    const __bf16* W12bt = ws + OFF_W12;
    const __bf16* W3bt  = ws + OFF_W3;

    // ---------- P0: stage cat = [img | loc] as bf16 (128 tokens) ----------
    {
        const float* srcs[2] = {img, loc};
        #pragma unroll
        for (int s = 0; s < 2; ++s) {
            const float* src = srcs[s] + tb * 64;
            #pragma unroll
            for (int it = 0; it < 8; ++it) {
                int u = (it * 256 + tid) * 4;         // 0..8188
                int t = u >> 6, c = u & 63;
                const float4 v = *(const float4*)(src + u);
                bf16x4 pk = {(__bf16)v.x, (__bf16)v.y, (__bf16)v.z, (__bf16)v.w};
                *(bf16x4*)(catL + t * 136 + s * 64 + c) = pk;
            }
        }
    }
    __syncthreads();

    // ---------- P1: wv 0,1 -> w11 cols (wv&1)*32..+32 (A-layout);
    //               wv 2,3 -> w21 cols (wv&1)*32..+32 (TRANSPOSED) ----------
    {
        const int isW21 = wv >> 1;
        const int cb0 = (wv & 1) * 32;
        const __bf16* Wbt = isW21 ? W21bt : W11bt;
        const float* bsel = isW21 ? b21 : b11;
        f32x4 a1[8][2] = {};
        #pragma unroll
        for (int kb = 0; kb < 4; ++kb) {
            #pragma unroll
            for (int nf = 0; nf < 2; ++nf) {
                bf16x8 bw = *(const bf16x8*)(Wbt + ((kb*4 + quad)*64 + cb0 + nf*16 + ln)*8);
                #pragma unroll
                for (int mf = 0; mf < 8; ++mf) {
                    bf16x8 af = *(const bf16x8*)(catL + (mf*16 + ln)*136 + kb*32 + quad*8);
                    a1[mf][nf] = MFMA16(af, bw, a1[mf][nf]);
                }
            }
        }
        if (!isW21) {
            #pragma unroll
            for (int nf = 0; nf < 2; ++nf) {
                int o = cb0 + nf*16 + ln;
                float cb = bsel[o];
                #pragma unroll
                for (int mf = 0; mf < 8; ++mf)
                    #pragma unroll
                    for (int r = 0; r < 4; ++r) {
                        int t = mf*16 + quad*4 + r;
                        float v = a1[mf][nf][r] + cb; v = v > 0.f ? v : 0.f;
                        w11L[t*72 + o] = (__bf16)v;
                    }
            }
        } else {
            #pragma unroll
            for (int nf = 0; nf < 2; ++nf) {
                int o = cb0 + nf*16 + ln;
                float cb = bsel[o];
                #pragma unroll
                for (int mf = 0; mf < 8; ++mf) {
                    bf16x4 pk;
                    #pragma unroll
                    for (int r = 0; r < 4; ++r) {
                        float v = a1[mf][nf][r] + cb; v = v > 0.f ? v : 0.f;
                        pk[r] = (__bf16)v;
                    }
                    *(bf16x4*)(w21T + o*132 + mf*16 + quad*4) = pk;
                }
            }
        }
    }
    __syncthreads();

    // ---------- P2: w12 = w11@W12 + b12 (no relu); wave computes its 16 cols ----------
    {
        float c12 = b12[ob + ln];
        f32x4 a12c[8] = {};
        #pragma unroll
        for (int kb = 0; kb < 2; ++kb) {
            bf16x8 bw = *(const bf16x8*)(W12bt + ((kb*4 + quad)*64 + ob + ln)*8);
            #pragma unroll
            for (int mf = 0; mf < 8; ++mf) {
                bf16x8 af = *(const bf16x8*)(w11L + (mf*16 + ln)*72 + kb*32 + quad*8);
                a12c[mf] = MFMA16(af, bw, a12c[mf]);
            }
        }
        #pragma unroll
        for (int mf = 0; mf < 8; ++mf)
            #pragma unroll
            for (int r = 0; r < 4; ++r) {
                int t = mf*16 + quad*4 + r;
                w12L[t*72 + ob + ln] = (__bf16)(a12c[mf][r] + c12);
            }
    }
    __syncthreads();

    // w12 A-fragments: constant MFMA A-operand for the whole K-loop (and the
    // bias-block A directly). Full 64-k rows per token, 128 tokens/wave.
    bf16x8 a12[8][2];
    #pragma unroll
    for (int mf = 0; mf < 8; ++mf)
        #pragma unroll
        for (int sub = 0; sub < 2; ++sub)
            a12[mf][sub] = *(const bf16x8*)(w12L + (mf*16 + ln)*72 + sub*32 + quad*8);

    // ---------- P3: barrier-free K-loop, depth-2 register pipeline ----------
    // fragment (c, s): k8 = c*16 + s*4 + quad -> one contiguous 1 KB wave-load.
    const __bf16* Bw = Bt22 + ((long)wv * 520 + quad) * 128 + ln * 8;

    bf16x8 B0_0, B0_1, B0_2, B0_3;
    bf16x8 B1_0, B1_1, B1_2, B1_3;
    bf16x8 B2_0, B2_1, B2_2, B2_3;

    f32x4 acc[8] = {};
    LOADCH(B0, 0); LOADCH(B1, 1);
    #pragma unroll 1
    for (int cc = 0; cc < 32; cc += 3) {
        if (cc + 2 < 32) LOADCH(B2, cc + 2);
        COMPUTE(B0, cc);
        if (cc + 3 < 32) LOADCH(B0, cc + 3);
        if (cc + 1 < 32) COMPUTE(B1, cc + 1);
        if (cc + 4 < 32) LOADCH(B1, cc + 4);
        if (cc + 2 < 32) COMPUTE(B2, cc + 2);
    }
    // bias rows: A = w12 directly, weight 1 (frags loaded now, buffers dead)
    {
        bf16x8 bb0 = *(const bf16x8*)(Bw + (512 + 0) * 128);
        bf16x8 bb1 = *(const bf16x8*)(Bw + (512 + 4) * 128);
        #pragma unroll
        for (int mf = 0; mf < 8; ++mf) {
            acc[mf] = MFMA16(a12[mf][0], bb0, acc[mf]);
            acc[mf] = MFMA16(a12[mf][1], bb1, acc[mf]);
        }
    }

    // ---------- P4: LayerNorm(64) + relu (cols split 16/wave -> LDS partials) ----------
    #pragma unroll
    for (int mf = 0; mf < 8; ++mf)
        #pragma unroll
        for (int r = 0; r < 4; ++r) {
            float v = acc[mf][r];
            float s1 = v, s2 = v*v;
            #pragma unroll
            for (int d = 1; d < 16; d <<= 1) {   // reduce this quad's 16 lanes
                s1 += __shfl_xor(s1, d, 64);
                s2 += __shfl_xor(s2, d, 64);
            }
            if (ln == 0) {
                int t = mf*16 + quad*4 + r;
                ps[t*4 + wv] = make_float2(s1, s2);
            }
        }
    __syncthreads();

    float gv = ln_g[ob + ln], bv = ln_b[ob + ln], b3v = b3[ob + ln];
    #pragma unroll
    for (int mf = 0; mf < 8; ++mf)
        #pragma unroll
        for (int r = 0; r < 4; ++r) {
            int t = mf*16 + quad*4 + r;
            float2 p0 = ps[t*4], p1 = ps[t*4 + 1], p2 = ps[t*4 + 2], p3 = ps[t*4 + 3];
            float mean = (p0.x + p1.x + p2.x + p3.x) * 0.015625f;
            float var  = (p0.y + p1.y + p2.y + p3.y) * 0.015625f - mean * mean;
            float inv  = rsqrtf(var + 1e-5f);
            float v = (acc[mf][r] - mean) * inv * gv + bv;
            v = v > 0.f ? v : 0.f;
            xL[t*72 + ob + ln] = (__bf16)v;
        }
    __syncthreads();

    // ---------- P5: out = x @ W3 + b3 (16 cols per wave, 128 tokens) ----------
    f32x4 a3[8] = {};
    #pragma unroll
    for (int kb = 0; kb < 2; ++kb) {
        bf16x8 bfr = *(const bf16x8*)(W3bt + ((kb*4 + quad)*64 + ob + ln)*8);
        #pragma unroll
        for (int mf = 0; mf < 8; ++mf) {
            bf16x8 af = *(const bf16x8*)(xL + (mf*16 + ln)*72 + kb*32 + quad*8);
            a3[mf] = MFMA16(af, bfr, a3[mf]);
        }
    }
    #pragma unroll
    for (int mf = 0; mf < 8; ++mf)
        #pragma unroll
        for (int r = 0; r < 4; ++r) {
            long t = tb + mf*16 + quad*4 + r;
            out[t*64 + ob + ln] = a3[mf][r] + b3v;
        }
}

extern "C" void kernel_launch(void* const* d_in, const int* in_sizes, int n_in,
                              void* d_out, int out_size, void* d_ws, size_t ws_size,
                              hipStream_t stream)
{
    const float* img  = (const float*)d_in[0];
    const float* loc  = (const float*)d_in[1];
    const float* W11  = (const float*)d_in[2];
    const float* b11  = (const float*)d_in[3];
    const float* W12  = (const float*)d_in[4];
    const float* b12  = (const float*)d_in[5];
    const float* W21  = (const float*)d_in[6];
    const float* b21  = (const float*)d_in[7];
    const float* W22  = (const float*)d_in[8];
    const float* b22  = (const float*)d_in[9];
    const float* ln_g = (const float*)d_in[10];
    const float* ln_b = (const float*)d_in[11];
    const float* W3   = (const float*)d_in[12];
    const float* b3   = (const float*)d_in[13];
    __bf16* ws = (__bf16*)d_ws;
    float*  o  = (float*)d_out;

    prep_kernel<<<71, 256, 0, stream>>>(W22, b22, W11, W21, W12, W3, ws);
    main_kernel<<<256, 256, 0, stream>>>(img, loc, b11, b12, b21, ln_g, ln_b, b3, ws, o);
}

// Round 12
// 114.664 us; speedup vs baseline: 1.7084x; 1.7084x over previous
//
#include <hip/hip_runtime.h>
#include <cstdint>

// Dynamic_MLP_C: fused bf16-MFMA implementation.
//
// Reformulation: x[t,o] = sum_k A[t,k] * B[k,o],  k = j*64+i  (K = 4160)
//   A[t, j*64+i] = w21[t,j] * w12[t,i]  (rank-1), bias rows A[t,4096+i]=w12[t,i].
// Re-association: x[t,o] = sum_j w21[t,j] * (w12[t,:] @ B_j)[o]
//   -> A-fragment = CONSTANT w12 regs; per j: 2 MFMAs -> m; acc += w21[t,j]*m.
//
// R7-R9: barrier-free K-loop, B straight from L2 to named VGPR buffers
// (532 KB fits per-XCD L2; prep layout -> 1 KB contiguous wave-loads).
// R9 = best (no spill, 128 VGPR, ~33 us main). R10 (depth-2) neutral;
// R11 (waves_per_eu + mf=8) re-spilled: the 128-VGPR cap is immovable.
// R12: attack the ~50% idle with TLP instead of registers. 32-token blocks
// (mf=2), grid 1024 -> 4 blocks/CU, 4 waves/SIMD (was 2). VGPR ~90 <= 128,
// LDS 23.5 KB x4 = 94 KB. L2 B-delivery doubles (545 MB ~ 16 us floor),
// still under the current 33 us wall; latency cover doubles.

typedef __bf16 bf16x4 __attribute__((ext_vector_type(4)));
typedef __bf16 bf16x8 __attribute__((ext_vector_type(8)));
typedef float  f32x4  __attribute__((ext_vector_type(4)));

#define MFMA16(A, B, C) __builtin_amdgcn_mfma_f32_16x16x32_bf16(A, B, C, 0, 0, 0)

// workspace element offsets (bf16 elements)
#define OFF_BT22 0         // K=4160 grouped layout, 266240 elems
#define OFF_W11  266240    // K=128,  8192 (frag layout)
#define OFF_W21  274432    // K=128,  8192
#define OFF_W12  282624    // K=64,   4096
#define OFF_W3   286720    // K=64,   4096

// prep: [64 k x 64 o] fp32 tile -> bf16.
//  W22/b22 tiles: grouped layout ws[((o>>4)*520 + k8)*128 + (o&15)*8 + (k&7)]
//  small weights: frag layout    ws[base + (k>>3)*512 + o*8 + (k&7)]
__global__ __launch_bounds__(256) void prep_kernel(
    const float* __restrict__ W22, const float* __restrict__ b22,
    const float* __restrict__ W11, const float* __restrict__ W21,
    const float* __restrict__ W12, const float* __restrict__ W3,
    __bf16* __restrict__ ws)
{
    __shared__ __bf16 T[64][72];
    const int b = blockIdx.x, tid = threadIdx.x;
    const float* src; long base = 0;
    if (b < 64)       { src = W22 + b * 4096; }
    else if (b == 64) { src = b22; }
    else if (b < 67)  { src = W11 + (b - 65) * 4096; base = OFF_W11 + (b - 65) * 4096; }
    else if (b < 69)  { src = W21 + (b - 67) * 4096; base = OFF_W21 + (b - 67) * 4096; }
    else if (b == 69) { src = W12;                   base = OFF_W12; }
    else              { src = W3;                    base = OFF_W3; }
    #pragma unroll
    for (int it = 0; it < 4; ++it) {
        int u = it * 1024 + tid * 4;
        int r = u >> 6, c = u & 63;
        const float4 v = *(const float4*)(src + u);
        T[r][c] = (__bf16)v.x; T[r][c + 1] = (__bf16)v.y;
        T[r][c + 2] = (__bf16)v.z; T[r][c + 3] = (__bf16)v.w;
    }
    __syncthreads();
    #pragma unroll
    for (int it = 0; it < 2; ++it) {
        int item = it * 256 + tid;
        int q = item >> 6, o = item & 63;
        bf16x8 pk;
        #pragma unroll
        for (int kj = 0; kj < 8; ++kj) pk[kj] = T[q * 8 + kj][o];
        long dstE;
        if (b <= 64) {
            int k8 = (b == 64 ? 512 : b * 8) + q;
            dstE = OFF_BT22 + ((long)(o >> 4) * 520 + k8) * 128 + (o & 15) * 8;
        } else {
            dstE = base + q * 512 + o * 8;
        }
        *(bf16x8*)(ws + dstE) = pk;
    }
}

// ---- register chunk-buffer machinery: named registers, token-pasted ----
#define LOADCH(buf, c) do {                                          \
    buf##_0 = *(const bf16x8*)(Bw + ((c)*16 +  0) * 128);            \
    buf##_1 = *(const bf16x8*)(Bw + ((c)*16 +  4) * 128);            \
    buf##_2 = *(const bf16x8*)(Bw + ((c)*16 +  8) * 128);            \
    buf##_3 = *(const bf16x8*)(Bw + ((c)*16 + 12) * 128);            \
} while (0)

#define COMPUTE_J(b0, b1, j) do {                                    \
    f32x4 w4[2];                                                     \
    _Pragma("unroll")                                                \
    for (int mf = 0; mf < 2; ++mf) {                                 \
        bf16x4 wv4 = *(const bf16x4*)(w21T + (j)*36 + mf*16 + quad*4);\
        w4[mf] = __builtin_convertvector(wv4, f32x4);                \
    }                                                                \
    _Pragma("unroll")                                                \
    for (int mf = 0; mf < 2; ++mf) {                                 \
        f32x4 fz = {};                                               \
        f32x4 m = MFMA16(a12[mf][0], b0, fz);                        \
        m       = MFMA16(a12[mf][1], b1, m);                         \
        _Pragma("unroll")                                            \
        for (int r = 0; r < 4; ++r)                                  \
            acc[mf][r] = fmaf(w4[mf][r], m[r], acc[mf][r]);          \
    }                                                                \
} while (0)

#define COMPUTE(buf, c) do {                                         \
    COMPUTE_J(buf##_0, buf##_1, (c)*2);                              \
    COMPUTE_J(buf##_2, buf##_3, (c)*2 + 1);                          \
} while (0)

__global__ __launch_bounds__(256, 4) void main_kernel(
    const float* __restrict__ img, const float* __restrict__ loc,
    const float* __restrict__ b11, const float* __restrict__ b12,
    const float* __restrict__ b21, const float* __restrict__ ln_g,
    const float* __restrict__ ln_b, const float* __restrict__ b3,
    const __bf16* __restrict__ ws, float* __restrict__ out)
{
    // LDS carve (23552 B, 4 blocks/CU):
    //  [0,8704)       catL [32][136] bf16
    //  [8704,13312)   w11L [32][72]  bf16   (reused as xL in P4/P5)
    //  [13312,17920)  w12L [32][72]  bf16
    //  [17920,22528)  w21T [64 j][36 t] bf16 (transposed; <=2-way on writes)
    //  [22528,23552)  ps   [32][4] float2   (LN cross-wave partials)
    __shared__ __align__(1024) char smem[23552];
    __bf16* catL = (__bf16*)smem;
    __bf16* w11L = (__bf16*)(smem + 8704);
    __bf16* w12L = (__bf16*)(smem + 13312);
    __bf16* w21T = (__bf16*)(smem + 17920);
    float2* ps   = (float2*)(smem + 22528);
    __bf16* xL   = w11L;

    const int tid  = threadIdx.x;
    const int wv   = tid >> 6;
    const int lane = tid & 63;
    const int ln   = lane & 15;     // A-row / C-col / B-col lane index
    const int quad = lane >> 4;     // k-quad / C-row group
    const int ob   = wv * 16;       // this wave's 16 o-cols (= col-group wv)
    const long tb  = (long)blockIdx.x * 32;

    const __bf16* Bt22  = ws + OFF_BT22;
    const __bf16* W11bt = ws + OFF_W11;
    const __bf16* W21bt = ws + OFF_W21;
    const __bf16* W12bt = ws + OFF_W12;
    const __bf16* W3bt  = ws + OFF_W3;

    // ---------- P0: stage cat = [img | loc] as bf16 (32 tokens) ----------
    {
        const float* srcs[2] = {img, loc};
        #pragma unroll
        for (int s = 0; s < 2; ++s) {
            const float* src = srcs[s] + tb * 64;
            #pragma unroll
            for (int it = 0; it < 2; ++it) {
                int u = (it * 256 + tid) * 4;         // 0..2044
                int t = u >> 6, c = u & 63;
                const float4 v = *(const float4*)(src + u);
                bf16x4 pk = {(__bf16)v.x, (__bf16)v.y, (__bf16)v.z, (__bf16)v.w};
                *(bf16x4*)(catL + t * 136 + s * 64 + c) = pk;
            }
        }
    }
    __syncthreads();

    // ---------- P1: wv 0,1 -> w11 cols (wv&1)*32..+32 (A-layout);
    //               wv 2,3 -> w21 cols (wv&1)*32..+32 (TRANSPOSED) ----------
    {
        const int isW21 = wv >> 1;
        const int cb0 = (wv & 1) * 32;
        const __bf16* Wbt = isW21 ? W21bt : W11bt;
        const float* bsel = isW21 ? b21 : b11;
        f32x4 a1[2][2] = {};
        #pragma unroll
        for (int kb = 0; kb < 4; ++kb) {
            bf16x8 af[2];
            #pragma unroll
            for (int mf = 0; mf < 2; ++mf)
                af[mf] = *(const bf16x8*)(catL + (mf*16 + ln)*136 + kb*32 + quad*8);
            #pragma unroll
            for (int nf = 0; nf < 2; ++nf) {
                bf16x8 bw = *(const bf16x8*)(Wbt + ((kb*4 + quad)*64 + cb0 + nf*16 + ln)*8);
                #pragma unroll
                for (int mf = 0; mf < 2; ++mf)
                    a1[mf][nf] = MFMA16(af[mf], bw, a1[mf][nf]);
            }
        }
        if (!isW21) {
            #pragma unroll
            for (int nf = 0; nf < 2; ++nf) {
                int o = cb0 + nf*16 + ln;
                float cb = bsel[o];
                #pragma unroll
                for (int mf = 0; mf < 2; ++mf)
                    #pragma unroll
                    for (int r = 0; r < 4; ++r) {
                        int t = mf*16 + quad*4 + r;
                        float v = a1[mf][nf][r] + cb; v = v > 0.f ? v : 0.f;
                        w11L[t*72 + o] = (__bf16)v;
                    }
            }
        } else {
            #pragma unroll
            for (int nf = 0; nf < 2; ++nf) {
                int o = cb0 + nf*16 + ln;
                float cb = bsel[o];
                #pragma unroll
                for (int mf = 0; mf < 2; ++mf) {
                    bf16x4 pk;
                    #pragma unroll
                    for (int r = 0; r < 4; ++r) {
                        float v = a1[mf][nf][r] + cb; v = v > 0.f ? v : 0.f;
                        pk[r] = (__bf16)v;
                    }
                    *(bf16x4*)(w21T + o*36 + mf*16 + quad*4) = pk;
                }
            }
        }
    }
    __syncthreads();

    // ---------- P2: w12 = w11@W12 + b12 (no relu); wave computes its 16 cols ----------
    {
        float c12 = b12[ob + ln];
        f32x4 a12c[2] = {};
        #pragma unroll
        for (int kb = 0; kb < 2; ++kb) {
            bf16x8 bw = *(const bf16x8*)(W12bt + ((kb*4 + quad)*64 + ob + ln)*8);
            #pragma unroll
            for (int mf = 0; mf < 2; ++mf) {
                bf16x8 af = *(const bf16x8*)(w11L + (mf*16 + ln)*72 + kb*32 + quad*8);
                a12c[mf] = MFMA16(af, bw, a12c[mf]);
            }
        }
        #pragma unroll
        for (int mf = 0; mf < 2; ++mf)
            #pragma unroll
            for (int r = 0; r < 4; ++r) {
                int t = mf*16 + quad*4 + r;
                w12L[t*72 + ob + ln] = (__bf16)(a12c[mf][r] + c12);
            }
    }
    __syncthreads();

    // w12 A-fragments: constant MFMA A-operand for the whole K-loop (and the
    // bias-block A directly). Full 64-k rows per token, 32 tokens/wave.
    bf16x8 a12[2][2];
    #pragma unroll
    for (int mf = 0; mf < 2; ++mf)
        #pragma unroll
        for (int sub = 0; sub < 2; ++sub)
            a12[mf][sub] = *(const bf16x8*)(w12L + (mf*16 + ln)*72 + sub*32 + quad*8);

    // ---------- P3: barrier-free K-loop, named VGPR double-buffer ----------
    // fragment (c, s): k8 = c*16 + s*4 + quad -> one contiguous 1 KB wave-load.
    const __bf16* Bw = Bt22 + ((long)wv * 520 + quad) * 128 + ln * 8;

    bf16x8 B0_0, B0_1, B0_2, B0_3;
    bf16x8 B1_0, B1_1, B1_2, B1_3;

    f32x4 acc[2] = {};
    LOADCH(B0, 0);
    #pragma unroll 1
    for (int cc = 0; cc < 32; cc += 2) {
        LOADCH(B1, cc + 1);
        COMPUTE(B0, cc);
        if (cc + 2 < 32) LOADCH(B0, cc + 2);
        COMPUTE(B1, cc + 1);
    }
    // bias rows: A = w12 directly, weight 1 (frags loaded now, buffers dead)
    {
        bf16x8 bb0 = *(const bf16x8*)(Bw + (512 + 0) * 128);
        bf16x8 bb1 = *(const bf16x8*)(Bw + (512 + 4) * 128);
        #pragma unroll
        for (int mf = 0; mf < 2; ++mf) {
            acc[mf] = MFMA16(a12[mf][0], bb0, acc[mf]);
            acc[mf] = MFMA16(a12[mf][1], bb1, acc[mf]);
        }
    }

    // ---------- P4: LayerNorm(64) + relu (cols split 16/wave -> LDS partials) ----------
    #pragma unroll
    for (int mf = 0; mf < 2; ++mf)
        #pragma unroll
        for (int r = 0; r < 4; ++r) {
            float v = acc[mf][r];
            float s1 = v, s2 = v*v;
            #pragma unroll
            for (int d = 1; d < 16; d <<= 1) {   // reduce this quad's 16 lanes
                s1 += __shfl_xor(s1, d, 64);
                s2 += __shfl_xor(s2, d, 64);
            }
            if (ln == 0) {
                int t = mf*16 + quad*4 + r;
                ps[t*4 + wv] = make_float2(s1, s2);
            }
        }
    __syncthreads();

    float gv = ln_g[ob + ln], bv = ln_b[ob + ln], b3v = b3[ob + ln];
    #pragma unroll
    for (int mf = 0; mf < 2; ++mf)
        #pragma unroll
        for (int r = 0; r < 4; ++r) {
            int t = mf*16 + quad*4 + r;
            float2 p0 = ps[t*4], p1 = ps[t*4 + 1], p2 = ps[t*4 + 2], p3 = ps[t*4 + 3];
            float mean = (p0.x + p1.x + p2.x + p3.x) * 0.015625f;
            float var  = (p0.y + p1.y + p2.y + p3.y) * 0.015625f - mean * mean;
            float inv  = rsqrtf(var + 1e-5f);
            float v = (acc[mf][r] - mean) * inv * gv + bv;
            v = v > 0.f ? v : 0.f;
            xL[t*72 + ob + ln] = (__bf16)v;
        }
    __syncthreads();

    // ---------- P5: out = x @ W3 + b3 (16 cols per wave, 32 tokens) ----------
    f32x4 a3[2] = {};
    #pragma unroll
    for (int kb = 0; kb < 2; ++kb) {
        bf16x8 bfr = *(const bf16x8*)(W3bt + ((kb*4 + quad)*64 + ob + ln)*8);
        #pragma unroll
        for (int mf = 0; mf < 2; ++mf) {
            bf16x8 af = *(const bf16x8*)(xL + (mf*16 + ln)*72 + kb*32 + quad*8);
            a3[mf] = MFMA16(af, bfr, a3[mf]);
        }
    }
    #pragma unroll
    for (int mf = 0; mf < 2; ++mf)
        #pragma unroll
        for (int r = 0; r < 4; ++r) {
            long t = tb + mf*16 + quad*4 + r;
            out[t*64 + ob + ln] = a3[mf][r] + b3v;
        }
}

extern "C" void kernel_launch(void* const* d_in, const int* in_sizes, int n_in,
                              void* d_out, int out_size, void* d_ws, size_t ws_size,
                              hipStream_t stream)
{
    const float* img  = (const float*)d_in[0];
    const float* loc  = (const float*)d_in[1];
    const float* W11  = (const float*)d_in[2];
    const float* b11  = (const float*)d_in[3];
    const float* W12  = (const float*)d_in[4];
    const float* b12  = (const float*)d_in[5];
    const float* W21  = (const float*)d_in[6];
    const float* b21  = (const float*)d_in[7];
    const float* W22  = (const float*)d_in[8];
    const float* b22  = (const float*)d_in[9];
    const float* ln_g = (const float*)d_in[10];
    const float* ln_b = (const float*)d_in[11];
    const float* W3   = (const float*)d_in[12];
    const float* b3   = (const float*)d_in[13];
    __bf16* ws = (__bf16*)d_ws;
    float*  o  = (float*)d_out;

    prep_kernel<<<71, 256, 0, stream>>>(W22, b22, W11, W21, W12, W3, ws);
    main_kernel<<<1024, 256, 0, stream>>>(img, loc, b11, b12, b21, ln_g, ln_b, b3, ws, o);
}